// Round 4
// baseline (528.855 us; speedup 1.0000x reference)
//
#include <hip/hip_runtime.h>
#include <hip/hip_bf16.h>

// Problem: B=8, T_OUT=256, T_IN=512, L=128, D_IN=128, D_ATT=128
// Inputs proven f32 at runtime by probe (R2); probe kept for robustness.
// R4 change: lstm_scan's per-step __syncthreads -> raw "s_waitcnt lgkmcnt(0); s_barrier".
// __syncthreads emits s_waitcnt vmcnt(0) before s_barrier, which drained the
// ~900-cyc xz prefetch load + x store every step (measured 2890 cyc/step vs
// ~1000 modeled). LDS-only wait is sufficient: h exchange is CU-local LDS;
// z loads / x stores are thread-private.
//
// ws layout (float elements):
#define CV_INP   256
#define CV_ATT   262400
#define CV_WK    786688
#define CV_WR    852224
#define CV_BIAS  917760
#define CV_W1    918272
#define CV_B1    934656
#define CV_W2    934784
#define CV_B2    951168
#define CV_W3    951296
#define CV_B3    951424
#define XZ_OFF   1048576
#define KEYS_OFF 2097152
#define X_OFF    2621440
// out layout: out(8,256,256) @0, h(8,128) @524288, c(8,128) @525312
#define OUT_H    524288
#define OUT_C    525312

// LDS-visibility-only barrier: does NOT drain vmcnt (unlike __syncthreads).
#define LDS_BARRIER() __asm__ __volatile__("s_waitcnt lgkmcnt(0)\n\ts_barrier" ::: "memory")

typedef _Float16 half2v __attribute__((ext_vector_type(2)));

__device__ __forceinline__ float fast_rcp(float x) { return __builtin_amdgcn_rcpf(x); }
__device__ __forceinline__ float fast_sig(float v) { return fast_rcp(1.f + __expf(-v)); }
__device__ __forceinline__ float fast_tanh(float v) { return 2.f * fast_rcp(1.f + __expf(-2.f * v)) - 1.f; }
__device__ __forceinline__ float bf2f(__hip_bfloat16 v) { return __bfloat162float(v); }

__device__ __forceinline__ float dot2acc(unsigned hbits, unsigned wbits, float acc) {
#if __has_builtin(__builtin_amdgcn_fdot2)
  half2v h = *(half2v*)&hbits, w = *(half2v*)&wbits;
  return __builtin_amdgcn_fdot2(h, w, acc, false);
#else
  half2v h = *(half2v*)&hbits, w = *(half2v*)&wbits;
  return acc + (float)h.x * (float)w.x + (float)h.y * (float)w.y;
#endif
}

__device__ __forceinline__ void store_out(void* out, int idx, float v, int isf32) {
  if (isf32) ((float*)out)[idx] = v;
  else ((__hip_bfloat16*)out)[idx] = __float2bfloat16(v);
}

// ---------------- Kernel 0: dtype probe ----------------
__global__ __launch_bounds__(256)
void dtype_probe(const unsigned short* __restrict__ att_raw, int* __restrict__ flag) {
  __shared__ int cnt[256];
  const int tid = threadIdx.x;
  int local = 0;
  for (int i = tid; i < 32768; i += 256) {
    unsigned short u = att_raw[i];
    if (((u >> 7) & 0xFF) == 0xFF) local++;
  }
  cnt[tid] = local;
  __syncthreads();
  for (int s = 128; s > 0; s >>= 1) {
    if (tid < s) cnt[tid] += cnt[tid + s];
    __syncthreads();
  }
  if (tid == 0) *flag = (cnt[0] > 8) ? 1 : 0;
}

// ---------------- Kernel 1: convert all inputs to f32 in ws ----------------
__device__ __forceinline__ void conv_seg(const void* src, float* __restrict__ dst, int n,
                                         int isf32, int g, int gs) {
  if (isf32) {
    const float* s = (const float*)src;
    for (int i = g; i < n; i += gs) dst[i] = s[i];
  } else {
    const __hip_bfloat16* s = (const __hip_bfloat16*)src;
    for (int i = g; i < n; i += gs) dst[i] = bf2f(s[i]);
  }
}

__global__ __launch_bounds__(256)
void convert_all(const void* inp, const void* att, const void* wk, const void* wr,
                 const void* bias, const void* w1, const void* b1, const void* w2,
                 const void* b2p, const void* w3, const void* b3p, float* __restrict__ ws) {
  const int isf32 = ((const int*)ws)[0];
  const int g = blockIdx.x * 256 + threadIdx.x, gs = gridDim.x * 256;
  conv_seg(inp,  ws + CV_INP,  262144, isf32, g, gs);
  conv_seg(att,  ws + CV_ATT,  524288, isf32, g, gs);
  conv_seg(wk,   ws + CV_WK,   65536,  isf32, g, gs);
  conv_seg(wr,   ws + CV_WR,   65536,  isf32, g, gs);
  conv_seg(bias, ws + CV_BIAS, 512,    isf32, g, gs);
  conv_seg(w1,   ws + CV_W1,   16384,  isf32, g, gs);
  conv_seg(b1,   ws + CV_B1,   128,    isf32, g, gs);
  conv_seg(w2,   ws + CV_W2,   16384,  isf32, g, gs);
  conv_seg(b2p,  ws + CV_B2,   128,    isf32, g, gs);
  conv_seg(w3,   ws + CV_W3,   128,    isf32, g, gs);
  conv_seg(b3p,  ws + CV_B3,   1,      isf32, g, gs);
}

// ---------------- Kernel A: keys = attended @ W1 + b1  (4096 rows x 128) ----------------
__global__ __launch_bounds__(256)
void keys_gemm(const float* __restrict__ ws) {
  const float* att = ws + CV_ATT;
  const float* W1  = ws + CV_W1;
  const float* b1  = ws + CV_B1;
  float* keys = (float*)ws + KEYS_OFF;
  __shared__ float ar[16][128];
  const int tid = threadIdx.x;
  const int row0 = blockIdx.x * 16;
  for (int i = tid; i < 16 * 128; i += 256) ar[i >> 7][i & 127] = att[row0 * 128 + i];
  __syncthreads();
  const int l = tid & 127, r0 = tid >> 7;
  float acc[8];
  const float bl = b1[l];
#pragma unroll
  for (int i = 0; i < 8; ++i) acc[i] = bl;
  for (int d = 0; d < 128; d += 4) {
    float w0 = W1[(d + 0) * 128 + l], w1 = W1[(d + 1) * 128 + l];
    float w2 = W1[(d + 2) * 128 + l], w3 = W1[(d + 3) * 128 + l];
#pragma unroll
    for (int i = 0; i < 8; ++i) {
      float4 a4 = *(const float4*)&ar[r0 + 2 * i][d];
      acc[i] += a4.x * w0 + a4.y * w1 + a4.z * w2 + a4.w * w3;
    }
  }
#pragma unroll
  for (int i = 0; i < 8; ++i) keys[(row0 + r0 + 2 * i) * 128 + l] = acc[i];
}

// ---------------- Kernel B: xz = inputs @ Wk + bias  (2048 rows x 512) ----------------
__global__ __launch_bounds__(256)
void xz_gemm(const float* __restrict__ ws) {
  const float* in   = ws + CV_INP;
  const float* Wk   = ws + CV_WK;
  const float* bias = ws + CV_BIAS;
  float* xz = (float*)ws + XZ_OFF;
  __shared__ float ar[8][128];
  const int tid = threadIdx.x;
  const int row0 = blockIdx.x * 8;
  for (int i = tid; i < 8 * 128; i += 256) ar[i >> 7][i & 127] = in[row0 * 128 + i];
  __syncthreads();
  float acc[8][2];
  const float bb0 = bias[tid], bb1 = bias[tid + 256];
#pragma unroll
  for (int r = 0; r < 8; ++r) { acc[r][0] = bb0; acc[r][1] = bb1; }
  for (int d = 0; d < 128; d += 4) {
    float w0a = Wk[(d + 0) * 512 + tid], w0b = Wk[(d + 0) * 512 + tid + 256];
    float w1a = Wk[(d + 1) * 512 + tid], w1b = Wk[(d + 1) * 512 + tid + 256];
    float w2a = Wk[(d + 2) * 512 + tid], w2b = Wk[(d + 2) * 512 + tid + 256];
    float w3a = Wk[(d + 3) * 512 + tid], w3b = Wk[(d + 3) * 512 + tid + 256];
#pragma unroll
    for (int r = 0; r < 8; ++r) {
      float4 a4 = *(const float4*)&ar[r][d];
      acc[r][0] += a4.x * w0a + a4.y * w1a + a4.z * w2a + a4.w * w3a;
      acc[r][1] += a4.x * w0b + a4.y * w1b + a4.z * w2b + a4.w * w3b;
    }
  }
#pragma unroll
  for (int r = 0; r < 8; ++r) {
    xz[(row0 + r) * 512 + tid] = acc[r][0];
    xz[(row0 + r) * 512 + tid + 256] = acc[r][1];
  }
}

// ---------------- Kernel C: LSTM scan v3 ----------------
// 1 block/batch, 128 threads. Thread j owns gate columns {j, j+128, j+256, j+384}.
// Wr packed f16x2 in 256 VGPRs, v_dot2_f32_f16. h broadcast as packed f16 LDS.
// Per-step barrier is LDS_BARRIER (no vmcnt drain): z prefetch/x store latency
// stays off the critical path.
__global__ __launch_bounds__(128, 1)
void lstm_scan(const float* __restrict__ ws, void* __restrict__ out) {
  const float* xz = ws + XZ_OFF;
  const float* Wr = ws + CV_WR;
  float* x = (float*)ws + X_OFF;
  const int isf32 = ((const int*)ws)[0];
  const int b = blockIdx.x;   // 0..7
  const int j = threadIdx.x;  // 0..127
  __shared__ unsigned hb[2][64];  // h as packed f16 pairs, double-buffered

  unsigned wr[4][64];
#pragma unroll
  for (int c = 0; c < 4; ++c) {
    const int col = j + 128 * c;
#pragma unroll
    for (int k2 = 0; k2 < 64; ++k2) {
      half2v w2 = { (_Float16)Wr[(2 * k2) * 512 + col], (_Float16)Wr[(2 * k2 + 1) * 512 + col] };
      wr[c][k2] = *(unsigned*)&w2;
    }
  }
  if (j < 64) hb[0][j] = 0u;  // h0 = 0
  float cst = 0.f;
  const float* xzb = xz + b * 256 * 512;
  float z0 = xzb[j], z1 = xzb[j + 128], z2 = xzb[j + 256], z3 = xzb[j + 384];
  LDS_BARRIER();

  float hval = 0.f;
  for (int t = 0; t < 256; ++t) {
    const unsigned* hcur = hb[t & 1];
    float a0 = 0.f, a1 = 0.f, a2 = 0.f, a3 = 0.f;
    float e0 = 0.f, e1 = 0.f, e2 = 0.f, e3 = 0.f;
#pragma unroll
    for (int i = 0; i < 16; ++i) {
      uint4 hv = ((const uint4*)hcur)[i];
      a0 = dot2acc(hv.x, wr[0][4 * i + 0], a0);
      a1 = dot2acc(hv.x, wr[1][4 * i + 0], a1);
      a2 = dot2acc(hv.x, wr[2][4 * i + 0], a2);
      a3 = dot2acc(hv.x, wr[3][4 * i + 0], a3);
      e0 = dot2acc(hv.y, wr[0][4 * i + 1], e0);
      e1 = dot2acc(hv.y, wr[1][4 * i + 1], e1);
      e2 = dot2acc(hv.y, wr[2][4 * i + 1], e2);
      e3 = dot2acc(hv.y, wr[3][4 * i + 1], e3);
      a0 = dot2acc(hv.z, wr[0][4 * i + 2], a0);
      a1 = dot2acc(hv.z, wr[1][4 * i + 2], a1);
      a2 = dot2acc(hv.z, wr[2][4 * i + 2], a2);
      a3 = dot2acc(hv.z, wr[3][4 * i + 2], a3);
      e0 = dot2acc(hv.w, wr[0][4 * i + 3], e0);
      e1 = dot2acc(hv.w, wr[1][4 * i + 3], e1);
      e2 = dot2acc(hv.w, wr[2][4 * i + 3], e2);
      e3 = dot2acc(hv.w, wr[3][4 * i + 3], e3);
    }
    const float zi = z0 + a0 + e0, zf = z1 + a1 + e1;
    const float zg = z2 + a2 + e2, zo = z3 + a3 + e3;
    if (t < 255) {
      const float* nxt = xzb + (t + 1) * 512;
      z0 = nxt[j]; z1 = nxt[j + 128]; z2 = nxt[j + 256]; z3 = nxt[j + 384];
    }
    cst = fast_sig(zf) * cst + fast_sig(zi) * fast_tanh(zg);
    hval = fast_sig(zo) * fast_tanh(cst);
    ((_Float16*)hb[(t + 1) & 1])[j] = (_Float16)hval;
    x[(b * 256 + t) * 128 + j] = hval;
    LDS_BARRIER();  // LDS visibility only; no vmcnt drain
  }
  store_out(out, OUT_H + b * 128 + j, hval, isf32);
  store_out(out, OUT_C + b * 128 + j, cst, isf32);
}

// ---------------- Kernel D: qproj + scores + softmax + weighted + concat ----------------
__global__ __launch_bounds__(256)
void attn_out_k(const float* __restrict__ ws, void* __restrict__ out) {
  const float* keys = ws + KEYS_OFF;
  const float* attc = ws + CV_ATT;
  const float* x    = ws + X_OFF;
  const float* W2c  = ws + CV_W2;
  const float* b2c  = ws + CV_B2;
  const float* W3c  = ws + CV_W3;
  const float* b3c  = ws + CV_B3;
  const int isf32 = ((const int*)ws)[0];
  __shared__ float qp[8][128];
  __shared__ float xr[8][128];
  __shared__ float sc[8][512];
  __shared__ float kt[64][129];  // +1 pad: 2-way bank alias only (free per m136)
  __shared__ float w3s[128];
  const int tid = threadIdx.x;
  const int b = blockIdx.x >> 5, qt = blockIdx.x & 31;
  const int q0 = qt * 8;
  const int l = tid & 127, r0 = tid >> 7;
  if (tid < 128) w3s[tid] = W3c[tid];
  for (int i = tid; i < 8 * 128; i += 256) xr[i >> 7][i & 127] = x[(b * 256 + q0) * 128 + i];
  __syncthreads();
  {
    float qa[4];
    const float bl = b2c[l];
#pragma unroll
    for (int i = 0; i < 4; ++i) qa[i] = bl;
    for (int d = 0; d < 128; d += 4) {
      float w0 = W2c[(d + 0) * 128 + l], w1 = W2c[(d + 1) * 128 + l];
      float w2v = W2c[(d + 2) * 128 + l], w3v = W2c[(d + 3) * 128 + l];
#pragma unroll
      for (int i = 0; i < 4; ++i) {
        float4 a4 = *(const float4*)&xr[r0 + 2 * i][d];
        qa[i] += a4.x * w0 + a4.y * w1 + a4.z * w2v + a4.w * w3v;
      }
    }
#pragma unroll
    for (int i = 0; i < 4; ++i) {
      int r = r0 + 2 * i;
      qp[r][l] = qa[i];
      store_out(out, (b * 256 + q0 + r) * 256 + l, xr[r][l], isf32);
    }
  }
  const float b3v = b3c[0];
  for (int kt0 = 0; kt0 < 512; kt0 += 64) {
    __syncthreads();
    for (int i = tid; i < 64 * 128; i += 256)
      kt[i >> 7][i & 127] = keys[(b * 512 + kt0 + (i >> 7)) * 128 + (i & 127)];
    __syncthreads();
#pragma unroll
    for (int pp = 0; pp < 2; ++pp) {
      const int p = tid + pp * 256;
      const int r = p >> 6, k = p & 63;
      float acc = 0.f;
      for (int ll = 0; ll < 128; ll += 4) {
        float4 q4 = *(const float4*)&qp[r][ll];
        float4 w4 = *(const float4*)&w3s[ll];
        acc += fast_tanh(kt[k][ll + 0] + q4.x) * w4.x
             + fast_tanh(kt[k][ll + 1] + q4.y) * w4.y
             + fast_tanh(kt[k][ll + 2] + q4.z) * w4.z
             + fast_tanh(kt[k][ll + 3] + q4.w) * w4.w;
      }
      sc[r][kt0 + k] = acc + b3v;
    }
  }
  __syncthreads();
  {
    const int wave = tid >> 6, lane = tid & 63;
    for (int r = wave; r < 8; r += 4) {
      float v[8];
#pragma unroll
      for (int i = 0; i < 8; ++i) v[i] = sc[r][lane + i * 64];
      float m = v[0];
#pragma unroll
      for (int i = 1; i < 8; ++i) m = fmaxf(m, v[i]);
#pragma unroll
      for (int off = 32; off > 0; off >>= 1) m = fmaxf(m, __shfl_xor(m, off));
      float e[8], s = 0.f;
#pragma unroll
      for (int i = 0; i < 8; ++i) { e[i] = __expf(v[i] - m); s += e[i]; }
#pragma unroll
      for (int off = 32; off > 0; off >>= 1) s += __shfl_xor(s, off);
      const float inv = fast_rcp(s);
#pragma unroll
      for (int i = 0; i < 8; ++i) sc[r][lane + i * 64] = e[i] * inv;
    }
  }
  __syncthreads();
  {
    const float* attb = attc + b * 512 * 128;
    float wa[4] = {0.f, 0.f, 0.f, 0.f};
    for (int k = 0; k < 512; k += 4) {
      float a0 = attb[(k + 0) * 128 + l];
      float a1 = attb[(k + 1) * 128 + l];
      float a2 = attb[(k + 2) * 128 + l];
      float a3 = attb[(k + 3) * 128 + l];
#pragma unroll
      for (int i = 0; i < 4; ++i) {
        float4 p4 = *(const float4*)&sc[r0 + 2 * i][k];
        wa[i] += p4.x * a0 + p4.y * a1 + p4.z * a2 + p4.w * a3;
      }
    }
#pragma unroll
    for (int i = 0; i < 4; ++i)
      store_out(out, (b * 256 + q0 + r0 + 2 * i) * 256 + 128 + l, wa[i], isf32);
  }
}

extern "C" void kernel_launch(void* const* d_in, const int* in_sizes, int n_in,
                              void* d_out, int out_size, void* d_ws, size_t ws_size,
                              hipStream_t stream) {
  float* ws = (float*)d_ws;
  hipLaunchKernelGGL(dtype_probe, dim3(1), dim3(256), 0, stream,
                     (const unsigned short*)d_in[1], (int*)d_ws);
  hipLaunchKernelGGL(convert_all, dim3(512), dim3(256), 0, stream,
                     d_in[0], d_in[1], d_in[2], d_in[3], d_in[4], d_in[5], d_in[6],
                     d_in[7], d_in[8], d_in[9], d_in[10], ws);
  hipLaunchKernelGGL(keys_gemm, dim3(256), dim3(256), 0, stream, ws);
  hipLaunchKernelGGL(xz_gemm,   dim3(256), dim3(256), 0, stream, ws);
  hipLaunchKernelGGL(lstm_scan, dim3(8),   dim3(128), 0, stream, ws, d_out);
  hipLaunchKernelGGL(attn_out_k, dim3(256), dim3(256), 0, stream, ws, d_out);
}

// Round 5
// 373.433 us; speedup vs baseline: 1.4162x; 1.4162x over previous
//
#include <hip/hip_runtime.h>
#include <hip/hip_bf16.h>

// Problem: B=8, T_OUT=256, T_IN=512, L=128, D_IN=128, D_ATT=128
// R5: MFMA-based LSTM scan. z^T = Wr^T(A-frags, regs) x h^T(B-frags, LDS),
// mfma_f32_16x16x32_f16, 2 blocks x 4 batches x 512 threads.
// xz stored f16 as [t][b][u][gate] by xz_gemm; x stored f16.
//
// ws layout (float elements):
#define CV_INP   256
#define CV_ATT   262400
#define CV_WK    786688
#define CV_WR    852224
#define CV_BIAS  917760
#define CV_W1    918272
#define CV_B1    934656
#define CV_W2    934784
#define CV_B2    951168
#define CV_W3    951296
#define CV_B3    951424
#define XZ_OFF   1048576   // f16[8*256*512] region
#define KEYS_OFF 2097152
#define X_OFF    2621440   // f16[8*256*128] region
// out layout: out(8,256,256) @0, h(8,128) @524288, c(8,128) @525312
#define OUT_H    524288
#define OUT_C    525312

#define LDS_BARRIER() __asm__ __volatile__("s_waitcnt lgkmcnt(0)\n\ts_barrier" ::: "memory")

typedef _Float16 f16x8 __attribute__((ext_vector_type(8)));
typedef float fx4 __attribute__((ext_vector_type(4)));

__device__ __forceinline__ float fast_rcp(float x) { return __builtin_amdgcn_rcpf(x); }
__device__ __forceinline__ float fast_sig(float v) { return fast_rcp(1.f + __expf(-v)); }
__device__ __forceinline__ float fast_tanh(float v) { return 2.f * fast_rcp(1.f + __expf(-2.f * v)) - 1.f; }
__device__ __forceinline__ float bf2f(__hip_bfloat16 v) { return __bfloat162float(v); }

__device__ __forceinline__ void store_out(void* out, int idx, float v, int isf32) {
  if (isf32) ((float*)out)[idx] = v;
  else ((__hip_bfloat16*)out)[idx] = __float2bfloat16(v);
}

// ---------------- Kernel 0: dtype probe ----------------
__global__ __launch_bounds__(256)
void dtype_probe(const unsigned short* __restrict__ att_raw, int* __restrict__ flag) {
  __shared__ int cnt[256];
  const int tid = threadIdx.x;
  int local = 0;
  for (int i = tid; i < 32768; i += 256) {
    unsigned short u = att_raw[i];
    if (((u >> 7) & 0xFF) == 0xFF) local++;
  }
  cnt[tid] = local;
  __syncthreads();
  for (int s = 128; s > 0; s >>= 1) {
    if (tid < s) cnt[tid] += cnt[tid + s];
    __syncthreads();
  }
  if (tid == 0) *flag = (cnt[0] > 8) ? 1 : 0;
}

// ---------------- Kernel 1: convert all inputs to f32 in ws ----------------
__device__ __forceinline__ void conv_seg(const void* src, float* __restrict__ dst, int n,
                                         int isf32, int g, int gs) {
  if (isf32) {
    const float* s = (const float*)src;
    for (int i = g; i < n; i += gs) dst[i] = s[i];
  } else {
    const __hip_bfloat16* s = (const __hip_bfloat16*)src;
    for (int i = g; i < n; i += gs) dst[i] = bf2f(s[i]);
  }
}

__global__ __launch_bounds__(256)
void convert_all(const void* inp, const void* att, const void* wk, const void* wr,
                 const void* bias, const void* w1, const void* b1, const void* w2,
                 const void* b2p, const void* w3, const void* b3p, float* __restrict__ ws) {
  const int isf32 = ((const int*)ws)[0];
  const int g = blockIdx.x * 256 + threadIdx.x, gs = gridDim.x * 256;
  conv_seg(inp,  ws + CV_INP,  262144, isf32, g, gs);
  conv_seg(att,  ws + CV_ATT,  524288, isf32, g, gs);
  conv_seg(wk,   ws + CV_WK,   65536,  isf32, g, gs);
  conv_seg(wr,   ws + CV_WR,   65536,  isf32, g, gs);
  conv_seg(bias, ws + CV_BIAS, 512,    isf32, g, gs);
  conv_seg(w1,   ws + CV_W1,   16384,  isf32, g, gs);
  conv_seg(b1,   ws + CV_B1,   128,    isf32, g, gs);
  conv_seg(w2,   ws + CV_W2,   16384,  isf32, g, gs);
  conv_seg(b2p,  ws + CV_B2,   128,    isf32, g, gs);
  conv_seg(w3,   ws + CV_W3,   128,    isf32, g, gs);
  conv_seg(b3p,  ws + CV_B3,   1,      isf32, g, gs);
}

// ---------------- Kernel A: keys = attended @ W1 + b1 ----------------
__global__ __launch_bounds__(256)
void keys_gemm(const float* __restrict__ ws) {
  const float* att = ws + CV_ATT;
  const float* W1  = ws + CV_W1;
  const float* b1  = ws + CV_B1;
  float* keys = (float*)ws + KEYS_OFF;
  __shared__ float ar[16][128];
  const int tid = threadIdx.x;
  const int row0 = blockIdx.x * 16;
  for (int i = tid; i < 16 * 128; i += 256) ar[i >> 7][i & 127] = att[row0 * 128 + i];
  __syncthreads();
  const int l = tid & 127, r0 = tid >> 7;
  float acc[8];
  const float bl = b1[l];
#pragma unroll
  for (int i = 0; i < 8; ++i) acc[i] = bl;
  for (int d = 0; d < 128; d += 4) {
    float w0 = W1[(d + 0) * 128 + l], w1 = W1[(d + 1) * 128 + l];
    float w2 = W1[(d + 2) * 128 + l], w3 = W1[(d + 3) * 128 + l];
#pragma unroll
    for (int i = 0; i < 8; ++i) {
      float4 a4 = *(const float4*)&ar[r0 + 2 * i][d];
      acc[i] += a4.x * w0 + a4.y * w1 + a4.z * w2 + a4.w * w3;
    }
  }
#pragma unroll
  for (int i = 0; i < 8; ++i) keys[(row0 + r0 + 2 * i) * 128 + l] = acc[i];
}

// ---------------- Kernel B: xz = inputs @ Wk + bias, stored f16 [t][b][u][gate] ----------------
__global__ __launch_bounds__(256)
void xz_gemm(const float* __restrict__ ws) {
  const float* in   = ws + CV_INP;
  const float* Wk   = ws + CV_WK;
  const float* bias = ws + CV_BIAS;
  _Float16* xz16 = (_Float16*)((float*)ws + XZ_OFF);
  __shared__ float ar[8][128];
  const int tid = threadIdx.x;
  const int row0 = blockIdx.x * 8;
  for (int i = tid; i < 8 * 128; i += 256) ar[i >> 7][i & 127] = in[row0 * 128 + i];
  __syncthreads();
  float acc[8][2];
  const float bb0 = bias[tid], bb1 = bias[tid + 256];
#pragma unroll
  for (int r = 0; r < 8; ++r) { acc[r][0] = bb0; acc[r][1] = bb1; }
  for (int d = 0; d < 128; d += 4) {
    float w0a = Wk[(d + 0) * 512 + tid], w0b = Wk[(d + 0) * 512 + tid + 256];
    float w1a = Wk[(d + 1) * 512 + tid], w1b = Wk[(d + 1) * 512 + tid + 256];
    float w2a = Wk[(d + 2) * 512 + tid], w2b = Wk[(d + 2) * 512 + tid + 256];
    float w3a = Wk[(d + 3) * 512 + tid], w3b = Wk[(d + 3) * 512 + tid + 256];
#pragma unroll
    for (int r = 0; r < 8; ++r) {
      float4 a4 = *(const float4*)&ar[r][d];
      acc[r][0] += a4.x * w0a + a4.y * w1a + a4.z * w2a + a4.w * w3a;
      acc[r][1] += a4.x * w0b + a4.y * w1b + a4.z * w2b + a4.w * w3b;
    }
  }
  // col = g*128 + u (Keras gate blocks). Store at ((t*8+b)*128+u)*4+g, f16.
  const int u = tid & 127, g0 = tid >> 7;
#pragma unroll
  for (int r = 0; r < 8; ++r) {
    const int row = row0 + r, b = row >> 8, t = row & 255;
    const int base = ((t * 8 + b) * 128 + u) * 4;
    xz16[base + g0]     = (_Float16)acc[r][0];
    xz16[base + g0 + 2] = (_Float16)acc[r][1];
  }
}

// ---------------- Kernel C: LSTM scan v4 (MFMA) ----------------
// Block = 4 batches, 512 threads (8 waves). Wave w owns units [16w,16w+16).
// z^T[gatecol][batch] = Wr^T x h^T: A=Wr^T in regs (f16), B=h^T from LDS.
// D-frag: col(lane&15)=batch, row(quad*4+reg)=unit-offset. dpp row_shr
// redistribution -> each lane owns one (batch,unit): c-state in 1 VGPR.
__global__ __launch_bounds__(512, 1)
void lstm_scan(const float* __restrict__ ws, void* __restrict__ out) {
  const float* Wrf = ws + CV_WR;
  const _Float16* xz16 = (const _Float16*)((const float*)ws + XZ_OFF);
  _Float16* x16 = (_Float16*)((float*)ws + X_OFF);
  const int isf32 = ((const int*)ws)[0];
  const int b_base = blockIdx.x * 4;
  const int tid = threadIdx.x;
  const int w = tid >> 6, lane = tid & 63;
  const int q = lane >> 4, p = lane & 15;
  const int b = p & 3, r = p >> 2;      // this lane's (batch,reg-slot) after dpp gather
  const int u = 16 * w + 4 * q + r;     // this lane's unit
  const int bg = b_base + b;

  __shared__ _Float16 hb[2][16 * 136];  // h^T rows=batch(16, 4 real), pad stride 136

  // A-frags: A[m=p][k=kt*32+q*8+j] = Wr[k][128c+16w+p], f16
  f16x8 afr[4][4];
#pragma unroll
  for (int c = 0; c < 4; ++c)
#pragma unroll
    for (int kt = 0; kt < 4; ++kt)
#pragma unroll
      for (int j = 0; j < 8; ++j)
        afr[c][kt][j] = (_Float16)Wrf[(kt * 32 + q * 8 + j) * 512 + 128 * c + 16 * w + p];

  {  // zero both H buffers (rows >=4 stay zero forever)
    _Float16* hp = &hb[0][0];
    for (int i = tid; i < 2 * 16 * 136; i += 512) hp[i] = (_Float16)0.f;
  }
  float cst = 0.f, hval = 0.f;
  // xz prefetch, 2 deep: 4 gates f16 = 8B per lane per step
  uint2 pf0 = *(const uint2*)(xz16 + ((0 * 8 + bg) * 128 + u) * 4);
  uint2 pf1 = *(const uint2*)(xz16 + ((1 * 8 + bg) * 128 + u) * 4);
  __syncthreads();

  for (int t = 0; t < 256; ++t) {
    const _Float16* hrow = &hb[t & 1][0];
    f16x8 bfr[4];
#pragma unroll
    for (int kt = 0; kt < 4; ++kt)
      bfr[kt] = *(const f16x8*)&hrow[p * 136 + kt * 32 + q * 8];
    fx4 acc[4];
#pragma unroll
    for (int c = 0; c < 4; ++c) acc[c] = (fx4)0.f;
#pragma unroll
    for (int kt = 0; kt < 4; ++kt)
#pragma unroll
      for (int c = 0; c < 4; ++c)
        acc[c] = __builtin_amdgcn_mfma_f32_16x16x32_f16(afr[c][kt], bfr[kt], acc[c], 0, 0, 0);

    // gather: lane p wants acc[c][r] from lane (q*16 + b) == p - 4r  -> row_shr:4r
    float z[4];
#pragma unroll
    for (int c = 0; c < 4; ++c) {
      float d1 = __int_as_float(__builtin_amdgcn_mov_dpp(__float_as_int(acc[c][1]), 0x114, 0xF, 0xF, true));
      float d2 = __int_as_float(__builtin_amdgcn_mov_dpp(__float_as_int(acc[c][2]), 0x118, 0xF, 0xF, true));
      float d3 = __int_as_float(__builtin_amdgcn_mov_dpp(__float_as_int(acc[c][3]), 0x11C, 0xF, 0xF, true));
      z[c] = (r == 0) ? acc[c][0] : (r == 1) ? d1 : (r == 2) ? d2 : d3;
    }

    uint2 cur = pf0;
    pf0 = pf1;
    const int t2 = (t + 2 < 256) ? t + 2 : 255;
    pf1 = *(const uint2*)(xz16 + ((t2 * 8 + bg) * 128 + u) * 4);

    const _Float16* cf = (const _Float16*)&cur;
    const float zi = z[0] + (float)cf[0];
    const float zf = z[1] + (float)cf[1];
    const float zg = z[2] + (float)cf[2];
    const float zo = z[3] + (float)cf[3];
    cst = fast_sig(zf) * cst + fast_sig(zi) * fast_tanh(zg);
    hval = fast_sig(zo) * fast_tanh(cst);
    hb[(t + 1) & 1][b * 136 + u] = (_Float16)hval;
    x16[(bg * 256 + t) * 128 + u] = (_Float16)hval;
    LDS_BARRIER();
  }
  store_out(out, OUT_H + bg * 128 + u, hval, isf32);
  store_out(out, OUT_C + bg * 128 + u, cst, isf32);
}

// ---------------- Kernel D: qproj + scores + softmax + weighted + concat ----------------
__global__ __launch_bounds__(256)
void attn_out_k(const float* __restrict__ ws, void* __restrict__ out) {
  const float* keys = ws + KEYS_OFF;
  const float* attc = ws + CV_ATT;
  const _Float16* x16 = (const _Float16*)((const float*)ws + X_OFF);
  const float* W2c  = ws + CV_W2;
  const float* b2c  = ws + CV_B2;
  const float* W3c  = ws + CV_W3;
  const float* b3c  = ws + CV_B3;
  const int isf32 = ((const int*)ws)[0];
  __shared__ float qp[8][128];
  __shared__ float xr[8][128];
  __shared__ float sc[8][512];
  __shared__ float kt[64][129];
  __shared__ float w3s[128];
  const int tid = threadIdx.x;
  const int b = blockIdx.x >> 5, qt = blockIdx.x & 31;
  const int q0 = qt * 8;
  const int l = tid & 127, r0 = tid >> 7;
  if (tid < 128) w3s[tid] = W3c[tid];
  for (int i = tid; i < 8 * 128; i += 256)
    xr[i >> 7][i & 127] = (float)x16[(b * 256 + q0) * 128 + i];
  __syncthreads();
  {
    float qa[4];
    const float bl = b2c[l];
#pragma unroll
    for (int i = 0; i < 4; ++i) qa[i] = bl;
    for (int d = 0; d < 128; d += 4) {
      float w0 = W2c[(d + 0) * 128 + l], w1 = W2c[(d + 1) * 128 + l];
      float w2v = W2c[(d + 2) * 128 + l], w3v = W2c[(d + 3) * 128 + l];
#pragma unroll
      for (int i = 0; i < 4; ++i) {
        float4 a4 = *(const float4*)&xr[r0 + 2 * i][d];
        qa[i] += a4.x * w0 + a4.y * w1 + a4.z * w2v + a4.w * w3v;
      }
    }
#pragma unroll
    for (int i = 0; i < 4; ++i) {
      int rr = r0 + 2 * i;
      qp[rr][l] = qa[i];
      store_out(out, (b * 256 + q0 + rr) * 256 + l, xr[rr][l], isf32);
    }
  }
  const float b3v = b3c[0];
  for (int kt0 = 0; kt0 < 512; kt0 += 64) {
    __syncthreads();
    for (int i = tid; i < 64 * 128; i += 256)
      kt[i >> 7][i & 127] = keys[(b * 512 + kt0 + (i >> 7)) * 128 + (i & 127)];
    __syncthreads();
#pragma unroll
    for (int pp = 0; pp < 2; ++pp) {
      const int pidx = tid + pp * 256;
      const int rr = pidx >> 6, k = pidx & 63;
      float acc = 0.f;
      for (int ll = 0; ll < 128; ll += 4) {
        float4 q4 = *(const float4*)&qp[rr][ll];
        float4 w4 = *(const float4*)&w3s[ll];
        acc += fast_tanh(kt[k][ll + 0] + q4.x) * w4.x
             + fast_tanh(kt[k][ll + 1] + q4.y) * w4.y
             + fast_tanh(kt[k][ll + 2] + q4.z) * w4.z
             + fast_tanh(kt[k][ll + 3] + q4.w) * w4.w;
      }
      sc[rr][kt0 + k] = acc + b3v;
    }
  }
  __syncthreads();
  {
    const int wave = tid >> 6, lane = tid & 63;
    for (int rr = wave; rr < 8; rr += 4) {
      float v[8];
#pragma unroll
      for (int i = 0; i < 8; ++i) v[i] = sc[rr][lane + i * 64];
      float m = v[0];
#pragma unroll
      for (int i = 1; i < 8; ++i) m = fmaxf(m, v[i]);
#pragma unroll
      for (int off = 32; off > 0; off >>= 1) m = fmaxf(m, __shfl_xor(m, off));
      float e[8], s = 0.f;
#pragma unroll
      for (int i = 0; i < 8; ++i) { e[i] = __expf(v[i] - m); s += e[i]; }
#pragma unroll
      for (int off = 32; off > 0; off >>= 1) s += __shfl_xor(s, off);
      const float inv = fast_rcp(s);
#pragma unroll
      for (int i = 0; i < 8; ++i) sc[rr][lane + i * 64] = e[i] * inv;
    }
  }
  __syncthreads();
  {
    const float* attb = attc + b * 512 * 128;
    float wa[4] = {0.f, 0.f, 0.f, 0.f};
    for (int k = 0; k < 512; k += 4) {
      float a0 = attb[(k + 0) * 128 + l];
      float a1 = attb[(k + 1) * 128 + l];
      float a2 = attb[(k + 2) * 128 + l];
      float a3 = attb[(k + 3) * 128 + l];
#pragma unroll
      for (int i = 0; i < 4; ++i) {
        float4 p4 = *(const float4*)&sc[r0 + 2 * i][k];
        wa[i] += p4.x * a0 + p4.y * a1 + p4.z * a2 + p4.w * a3;
      }
    }
#pragma unroll
    for (int i = 0; i < 4; ++i)
      store_out(out, (b * 256 + q0 + r0 + 2 * i) * 256 + 128 + l, wa[i], isf32);
  }
}

extern "C" void kernel_launch(void* const* d_in, const int* in_sizes, int n_in,
                              void* d_out, int out_size, void* d_ws, size_t ws_size,
                              hipStream_t stream) {
  float* ws = (float*)d_ws;
  hipLaunchKernelGGL(dtype_probe, dim3(1), dim3(256), 0, stream,
                     (const unsigned short*)d_in[1], (int*)d_ws);
  hipLaunchKernelGGL(convert_all, dim3(512), dim3(256), 0, stream,
                     d_in[0], d_in[1], d_in[2], d_in[3], d_in[4], d_in[5], d_in[6],
                     d_in[7], d_in[8], d_in[9], d_in[10], ws);
  hipLaunchKernelGGL(keys_gemm, dim3(256), dim3(256), 0, stream, ws);
  hipLaunchKernelGGL(xz_gemm,   dim3(256), dim3(256), 0, stream, ws);
  hipLaunchKernelGGL(lstm_scan, dim3(2),   dim3(512), 0, stream, ws, d_out);
  hipLaunchKernelGGL(attn_out_k, dim3(256), dim3(256), 0, stream, ws, d_out);
}

// Round 6
// 318.314 us; speedup vs baseline: 1.6614x; 1.1732x over previous
//
#include <hip/hip_runtime.h>
#include <hip/hip_bf16.h>

// Problem: B=8, T_OUT=256, T_IN=512, L=128, D_IN=128, D_ATT=128
// Dtype settled (R2-R5): inputs f32, outputs f32 (test label's "bf16" is the
// error-floor mode). Probe/convert deleted; 3 kernels total.
// R6: lstm B-frag broadcast (lanes p>=4 read rows p&3 -> same-address LDS
// broadcast, ~3x less LDS pipe), 3-deep xz prefetch, fused prologue.
//
// ws layout (float elements):
#define XZ_OFF   1048576   // f16[8*256*512] region (2 MB)
#define KEYS_OFF 2097152   // f32[8*512*128]
#define X_OFF    2621440   // f16[8*256*128] region
// out layout (f32): out(8,256,256) @0, h(8,128) @524288, c(8,128) @525312
#define OUT_H    524288
#define OUT_C    525312

#define LDS_BARRIER() __asm__ __volatile__("s_waitcnt lgkmcnt(0)\n\ts_barrier" ::: "memory")

typedef _Float16 f16x8 __attribute__((ext_vector_type(8)));
typedef float fx4 __attribute__((ext_vector_type(4)));

__device__ __forceinline__ float fast_rcp(float x) { return __builtin_amdgcn_rcpf(x); }
__device__ __forceinline__ float fast_sig(float v) { return fast_rcp(1.f + __expf(-v)); }
__device__ __forceinline__ float fast_tanh(float v) { return 2.f * fast_rcp(1.f + __expf(-2.f * v)) - 1.f; }

// ---------------- Kernel 1: prologue = keys_gemm (blocks 0-255) + xz_gemm (256-511) ----------------
__global__ __launch_bounds__(256)
void prologue_k(const float* __restrict__ inp, const float* __restrict__ att,
                const float* __restrict__ Wk, const float* __restrict__ bias,
                const float* __restrict__ W1, const float* __restrict__ b1,
                float* __restrict__ ws) {
  __shared__ float ar[16][128];
  const int tid = threadIdx.x;
  if (blockIdx.x < 256) {
    // ---- keys = attended @ W1 + b1 (16 rows/block) ----
    float* keys = ws + KEYS_OFF;
    const int row0 = blockIdx.x * 16;
    for (int i = tid; i < 16 * 128; i += 256) ar[i >> 7][i & 127] = att[row0 * 128 + i];
    __syncthreads();
    const int l = tid & 127, r0 = tid >> 7;
    float acc[8];
    const float bl = b1[l];
#pragma unroll
    for (int i = 0; i < 8; ++i) acc[i] = bl;
    for (int d = 0; d < 128; d += 4) {
      float w0 = W1[(d + 0) * 128 + l], w1 = W1[(d + 1) * 128 + l];
      float w2 = W1[(d + 2) * 128 + l], w3 = W1[(d + 3) * 128 + l];
#pragma unroll
      for (int i = 0; i < 8; ++i) {
        float4 a4 = *(const float4*)&ar[r0 + 2 * i][d];
        acc[i] += a4.x * w0 + a4.y * w1 + a4.z * w2 + a4.w * w3;
      }
    }
#pragma unroll
    for (int i = 0; i < 8; ++i) keys[(row0 + r0 + 2 * i) * 128 + l] = acc[i];
  } else {
    // ---- xz = inputs @ Wk + bias, stored f16 [t][b][u][gate] (8 rows/block) ----
    _Float16* xz16 = (_Float16*)(ws + XZ_OFF);
    const int row0 = (blockIdx.x - 256) * 8;
    for (int i = tid; i < 8 * 128; i += 256) ar[i >> 7][i & 127] = inp[row0 * 128 + i];
    __syncthreads();
    float acc[8][2];
    const float bb0 = bias[tid], bb1 = bias[tid + 256];
#pragma unroll
    for (int r = 0; r < 8; ++r) { acc[r][0] = bb0; acc[r][1] = bb1; }
    for (int d = 0; d < 128; d += 4) {
      float w0a = Wk[(d + 0) * 512 + tid], w0b = Wk[(d + 0) * 512 + tid + 256];
      float w1a = Wk[(d + 1) * 512 + tid], w1b = Wk[(d + 1) * 512 + tid + 256];
      float w2a = Wk[(d + 2) * 512 + tid], w2b = Wk[(d + 2) * 512 + tid + 256];
      float w3a = Wk[(d + 3) * 512 + tid], w3b = Wk[(d + 3) * 512 + tid + 256];
#pragma unroll
      for (int r = 0; r < 8; ++r) {
        float4 a4 = *(const float4*)&ar[r][d];
        acc[r][0] += a4.x * w0a + a4.y * w1a + a4.z * w2a + a4.w * w3a;
        acc[r][1] += a4.x * w0b + a4.y * w1b + a4.z * w2b + a4.w * w3b;
      }
    }
    // col = g*128 + u (Keras gate blocks) -> ((t*8+b)*128+u)*4+g, f16
    const int u = tid & 127, g0 = tid >> 7;
#pragma unroll
    for (int r = 0; r < 8; ++r) {
      const int row = row0 + r, b = row >> 8, t = row & 255;
      const int base = ((t * 8 + b) * 128 + u) * 4;
      xz16[base + g0]     = (_Float16)acc[r][0];
      xz16[base + g0 + 2] = (_Float16)acc[r][1];
    }
  }
}

// ---------------- Kernel 2: LSTM scan v5 (MFMA + broadcast-B) ----------------
// Block = 4 batches, 512 threads (8 waves). Wave w owns units [16w,16w+16).
// A = Wr^T (f16 regs), B = h^T from LDS with lanes p>=4 reading rows p&3
// (duplicated B-cols give D[m][col] = z[m][col&3]; dpp gather pulls from lane
// p-4r whose col&3 == p&3 -> identical results, ~3x less LDS-pipe cost).
__global__ __launch_bounds__(512, 1)
void lstm_scan(const float* __restrict__ Wrf, const float* __restrict__ ws,
               float* __restrict__ out) {
  const _Float16* xz16 = (const _Float16*)(ws + XZ_OFF);
  _Float16* x16 = (_Float16*)((float*)ws + X_OFF);
  const int b_base = blockIdx.x * 4;
  const int tid = threadIdx.x;
  const int w = tid >> 6, lane = tid & 63;
  const int q = lane >> 4, p = lane & 15;
  const int b = p & 3, r = p >> 2;      // lane's (batch, reg-slot) after dpp gather
  const int u = 16 * w + 4 * q + r;     // lane's unit
  const int bg = b_base + b;

  __shared__ _Float16 hb[2][552];       // 4 rows x stride 136 (16B-aligned), dbuf

  // A-frags: A[m=p][k=kt*32+q*8+j] = Wr[k][128c+16w+p]
  f16x8 afr[4][4];
#pragma unroll
  for (int c = 0; c < 4; ++c)
#pragma unroll
    for (int kt = 0; kt < 4; ++kt)
#pragma unroll
      for (int j = 0; j < 8; ++j)
        afr[c][kt][j] = (_Float16)Wrf[(kt * 32 + q * 8 + j) * 512 + 128 * c + 16 * w + p];

  {
    _Float16* hp = &hb[0][0];
    for (int i = tid; i < 2 * 552; i += 512) hp[i] = (_Float16)0.f;
  }
  float cst = 0.f, hval = 0.f;
  // xz prefetch, 3 deep: 8B per lane per step, stride 4096 f16 per t
  const _Float16* xp = xz16 + (bg * 128 + u) * 4;
  uint2 pf0 = *(const uint2*)(xp);
  uint2 pf1 = *(const uint2*)(xp + 4096);
  uint2 pf2 = *(const uint2*)(xp + 8192);
  __syncthreads();

  const int brow = (p & 3) * 136;  // broadcast row: lanes p>=4 mirror p&3
  for (int t = 0; t < 256; ++t) {
    const _Float16* hrow = &hb[t & 1][brow];
    f16x8 bfr[4];
#pragma unroll
    for (int kt = 0; kt < 4; ++kt)
      bfr[kt] = *(const f16x8*)&hrow[kt * 32 + q * 8];
    fx4 acc[4];
#pragma unroll
    for (int c = 0; c < 4; ++c) acc[c] = (fx4)0.f;
#pragma unroll
    for (int kt = 0; kt < 4; ++kt)
#pragma unroll
      for (int c = 0; c < 4; ++c)
        acc[c] = __builtin_amdgcn_mfma_f32_16x16x32_f16(afr[c][kt], bfr[kt], acc[c], 0, 0, 0);

    // gather: lane p takes acc[c][r] from lane p-4r (row_shr:4r)
    float z[4];
#pragma unroll
    for (int c = 0; c < 4; ++c) {
      float d1 = __int_as_float(__builtin_amdgcn_mov_dpp(__float_as_int(acc[c][1]), 0x114, 0xF, 0xF, true));
      float d2 = __int_as_float(__builtin_amdgcn_mov_dpp(__float_as_int(acc[c][2]), 0x118, 0xF, 0xF, true));
      float d3 = __int_as_float(__builtin_amdgcn_mov_dpp(__float_as_int(acc[c][3]), 0x11C, 0xF, 0xF, true));
      z[c] = (r == 0) ? acc[c][0] : (r == 1) ? d1 : (r == 2) ? d2 : d3;
    }

    uint2 cur = pf0;
    pf0 = pf1; pf1 = pf2;
    const int t3 = (t + 3 < 256) ? t + 3 : 255;
    pf2 = *(const uint2*)(xp + t3 * 4096);

    const _Float16* cf = (const _Float16*)&cur;
    const float zi = z[0] + (float)cf[0];
    const float zf = z[1] + (float)cf[1];
    const float zg = z[2] + (float)cf[2];
    const float zo = z[3] + (float)cf[3];
    cst = fast_sig(zf) * cst + fast_sig(zi) * fast_tanh(zg);
    hval = fast_sig(zo) * fast_tanh(cst);
    hb[(t + 1) & 1][b * 136 + u] = (_Float16)hval;
    x16[(bg * 256 + t) * 128 + u] = (_Float16)hval;
    LDS_BARRIER();  // LDS visibility only; no vmcnt drain
  }
  out[OUT_H + bg * 128 + u] = hval;
  out[OUT_C + bg * 128 + u] = cst;
}

// ---------------- Kernel 3: qproj + scores + softmax + weighted + concat ----------------
__global__ __launch_bounds__(256)
void attn_out_k(const float* __restrict__ att, const float* __restrict__ W2c,
                const float* __restrict__ b2c, const float* __restrict__ W3c,
                const float* __restrict__ b3c, const float* __restrict__ ws,
                float* __restrict__ out) {
  const float* keys = ws + KEYS_OFF;
  const _Float16* x16 = (const _Float16*)(ws + X_OFF);
  __shared__ float qp[8][128];
  __shared__ float xr[8][128];
  __shared__ float sc[8][512];
  __shared__ float kt[64][129];
  __shared__ float w3s[128];
  const int tid = threadIdx.x;
  const int b = blockIdx.x >> 5, qt = blockIdx.x & 31;
  const int q0 = qt * 8;
  const int l = tid & 127, r0 = tid >> 7;
  if (tid < 128) w3s[tid] = W3c[tid];
  for (int i = tid; i < 8 * 128; i += 256)
    xr[i >> 7][i & 127] = (float)x16[(b * 256 + q0) * 128 + i];
  __syncthreads();
  {
    float qa[4];
    const float bl = b2c[l];
#pragma unroll
    for (int i = 0; i < 4; ++i) qa[i] = bl;
    for (int d = 0; d < 128; d += 4) {
      float w0 = W2c[(d + 0) * 128 + l], w1 = W2c[(d + 1) * 128 + l];
      float w2v = W2c[(d + 2) * 128 + l], w3v = W2c[(d + 3) * 128 + l];
#pragma unroll
      for (int i = 0; i < 4; ++i) {
        float4 a4 = *(const float4*)&xr[r0 + 2 * i][d];
        qa[i] += a4.x * w0 + a4.y * w1 + a4.z * w2v + a4.w * w3v;
      }
    }
#pragma unroll
    for (int i = 0; i < 4; ++i) {
      int rr = r0 + 2 * i;
      qp[rr][l] = qa[i];
      out[(b * 256 + q0 + rr) * 256 + l] = xr[rr][l];
    }
  }
  const float b3v = b3c[0];
  for (int kt0 = 0; kt0 < 512; kt0 += 64) {
    __syncthreads();
    for (int i = tid; i < 64 * 128; i += 256)
      kt[i >> 7][i & 127] = keys[(b * 512 + kt0 + (i >> 7)) * 128 + (i & 127)];
    __syncthreads();
#pragma unroll
    for (int pp = 0; pp < 2; ++pp) {
      const int pidx = tid + pp * 256;
      const int rr = pidx >> 6, k = pidx & 63;
      float acc = 0.f;
      for (int ll = 0; ll < 128; ll += 4) {
        float4 q4 = *(const float4*)&qp[rr][ll];
        float4 w4 = *(const float4*)&w3s[ll];
        acc += fast_tanh(kt[k][ll + 0] + q4.x) * w4.x
             + fast_tanh(kt[k][ll + 1] + q4.y) * w4.y
             + fast_tanh(kt[k][ll + 2] + q4.z) * w4.z
             + fast_tanh(kt[k][ll + 3] + q4.w) * w4.w;
      }
      sc[rr][kt0 + k] = acc + b3v;
    }
  }
  __syncthreads();
  {
    const int wave = tid >> 6, lane = tid & 63;
    for (int rr = wave; rr < 8; rr += 4) {
      float v[8];
#pragma unroll
      for (int i = 0; i < 8; ++i) v[i] = sc[rr][lane + i * 64];
      float m = v[0];
#pragma unroll
      for (int i = 1; i < 8; ++i) m = fmaxf(m, v[i]);
#pragma unroll
      for (int off = 32; off > 0; off >>= 1) m = fmaxf(m, __shfl_xor(m, off));
      float e[8], s = 0.f;
#pragma unroll
      for (int i = 0; i < 8; ++i) { e[i] = __expf(v[i] - m); s += e[i]; }
#pragma unroll
      for (int off = 32; off > 0; off >>= 1) s += __shfl_xor(s, off);
      const float inv = fast_rcp(s);
#pragma unroll
      for (int i = 0; i < 8; ++i) sc[rr][lane + i * 64] = e[i] * inv;
    }
  }
  __syncthreads();
  {
    const float* attb = att + b * 512 * 128;
    float wa[4] = {0.f, 0.f, 0.f, 0.f};
    for (int k = 0; k < 512; k += 4) {
      float a0 = attb[(k + 0) * 128 + l];
      float a1 = attb[(k + 1) * 128 + l];
      float a2 = attb[(k + 2) * 128 + l];
      float a3 = attb[(k + 3) * 128 + l];
#pragma unroll
      for (int i = 0; i < 4; ++i) {
        float4 p4 = *(const float4*)&sc[r0 + 2 * i][k];
        wa[i] += p4.x * a0 + p4.y * a1 + p4.z * a2 + p4.w * a3;
      }
    }
#pragma unroll
    for (int i = 0; i < 4; ++i)
      out[(b * 256 + q0 + r0 + 2 * i) * 256 + 128 + l] = wa[i];
  }
}

extern "C" void kernel_launch(void* const* d_in, const int* in_sizes, int n_in,
                              void* d_out, int out_size, void* d_ws, size_t ws_size,
                              hipStream_t stream) {
  const float* inputs   = (const float*)d_in[0];
  const float* attended = (const float*)d_in[1];
  const float* Wk       = (const float*)d_in[2];
  const float* Wr       = (const float*)d_in[3];
  const float* bias     = (const float*)d_in[4];
  const float* W1       = (const float*)d_in[5];
  const float* b1       = (const float*)d_in[6];
  const float* W2       = (const float*)d_in[7];
  const float* b2       = (const float*)d_in[8];
  const float* W3       = (const float*)d_in[9];
  const float* b3       = (const float*)d_in[10];
  float* out = (float*)d_out;
  float* ws = (float*)d_ws;

  hipLaunchKernelGGL(prologue_k, dim3(512), dim3(256), 0, stream,
                     inputs, attended, Wk, bias, W1, b1, ws);
  hipLaunchKernelGGL(lstm_scan, dim3(2), dim3(512), 0, stream, Wr, ws, out);
  hipLaunchKernelGGL(attn_out_k, dim3(256), dim3(256), 0, stream,
                     attended, W2, b2, W3, b3, ws, out);
}

// Round 7
// 307.679 us; speedup vs baseline: 1.7189x; 1.0346x over previous
//
#include <hip/hip_runtime.h>
#include <hip/hip_bf16.h>

// Problem: B=8, T_OUT=256, T_IN=512, L=128, D_IN=128, D_ATT=128 (f32 in/out).
// R7: scan row-remap (dpp gather -> 12 cndmask), persistent-zero MFMA C
// (no per-step acc init), keys GEMM fused into the lstm launch (blocks 2-257
// run under the scan's shadow), attn split to 512 blocks for 2/CU occupancy.
//
// ws layout (float elements):
#define XZ_OFF   1048576   // f16[8*256*512] region (2 MB)
#define KEYS_OFF 2097152   // f32[8*512*128]
#define X_OFF    2621440   // f16[8*256*128] region
// out layout (f32): out(8,256,256) @0, h(8,128) @524288, c(8,128) @525312
#define OUT_H    524288
#define OUT_C    525312

#define LDS_BARRIER() __asm__ __volatile__("s_waitcnt lgkmcnt(0)\n\ts_barrier" ::: "memory")

typedef _Float16 f16x8 __attribute__((ext_vector_type(8)));
typedef float fx4 __attribute__((ext_vector_type(4)));

__device__ __forceinline__ float fast_rcp(float x) { return __builtin_amdgcn_rcpf(x); }
__device__ __forceinline__ float fast_sig(float v) { return fast_rcp(1.f + __expf(-v)); }
__device__ __forceinline__ float fast_tanh(float v) { return 2.f * fast_rcp(1.f + __expf(-2.f * v)) - 1.f; }

// ---------------- Kernel 1: xz = inputs @ Wk + bias, f16 [t][b][u][gate] ----------------
__global__ __launch_bounds__(256)
void xz_prologue(const float* __restrict__ inp, const float* __restrict__ Wk,
                 const float* __restrict__ bias, float* __restrict__ ws) {
  _Float16* xz16 = (_Float16*)(ws + XZ_OFF);
  __shared__ float ar[8][128];
  const int tid = threadIdx.x;
  const int row0 = blockIdx.x * 8;
  for (int i = tid; i < 8 * 128; i += 256) ar[i >> 7][i & 127] = inp[row0 * 128 + i];
  __syncthreads();
  float acc[8][2];
  const float bb0 = bias[tid], bb1 = bias[tid + 256];
#pragma unroll
  for (int r = 0; r < 8; ++r) { acc[r][0] = bb0; acc[r][1] = bb1; }
  for (int d = 0; d < 128; d += 4) {
    float w0a = Wk[(d + 0) * 512 + tid], w0b = Wk[(d + 0) * 512 + tid + 256];
    float w1a = Wk[(d + 1) * 512 + tid], w1b = Wk[(d + 1) * 512 + tid + 256];
    float w2a = Wk[(d + 2) * 512 + tid], w2b = Wk[(d + 2) * 512 + tid + 256];
    float w3a = Wk[(d + 3) * 512 + tid], w3b = Wk[(d + 3) * 512 + tid + 256];
#pragma unroll
    for (int r = 0; r < 8; ++r) {
      float4 a4 = *(const float4*)&ar[r][d];
      acc[r][0] += a4.x * w0a + a4.y * w1a + a4.z * w2a + a4.w * w3a;
      acc[r][1] += a4.x * w0b + a4.y * w1b + a4.z * w2b + a4.w * w3b;
    }
  }
  // Wk col = g*128 + u (Keras gate blocks) -> ((t*8+b)*128+u)*4+g
  const int u = tid & 127, g0 = tid >> 7;
#pragma unroll
  for (int r = 0; r < 8; ++r) {
    const int row = row0 + r, b = row >> 8, t = row & 255;
    const int base = ((t * 8 + b) * 128 + u) * 4;
    xz16[base + g0]     = (_Float16)acc[r][0];
    xz16[base + g0 + 2] = (_Float16)acc[r][1];
  }
}

// ---------------- Kernel 2: LSTM scan v6 (MFMA, remapped rows) + keys GEMM ----------------
// Blocks 0-1: scan (4 batches each). Blocks 2-257: keys = attended @ W1 + b1
// (16 rows each) — independent work that runs on idle CUs under the scan.
// Scan row-map: MFMA row m = 4*du + g (g = m&3 gate, du = m>>2); MFMA i covers
// units 16w+4i+du. Lane (q,p) D-regs r = rows 4q+r = gates r of unit 16w+4i+q.
// Lane's own set: i = p>>2 (12 cndmask), batch = p&3 (B-cols broadcast).
__global__ __launch_bounds__(512, 1)
void lstm_scan(const float* __restrict__ Wrf, const float* __restrict__ att,
               const float* __restrict__ W1, const float* __restrict__ b1,
               const float* __restrict__ ws, float* __restrict__ out) {
  __shared__ _Float16 hb[2][552];       // 4 rows x stride 136, dbuf
  __shared__ float ar[16][128];         // keys staging (blocks >= 2 only)
  const int tid = threadIdx.x;

  if (blockIdx.x >= 2) {
    // ---- keys GEMM: 16 rows, 512 threads ----
    float* keys = (float*)ws + KEYS_OFF;
    const int row0 = (blockIdx.x - 2) * 16;
    for (int i = tid; i < 16 * 128; i += 512) ar[i >> 7][i & 127] = att[row0 * 128 + i];
    __syncthreads();
    const int l = tid & 127, r0 = tid >> 7;  // r0 in 0..3
    float acc[4];
    const float bl = b1[l];
#pragma unroll
    for (int i = 0; i < 4; ++i) acc[i] = bl;
    for (int d = 0; d < 128; d += 4) {
      float w0 = W1[(d + 0) * 128 + l], w1 = W1[(d + 1) * 128 + l];
      float w2 = W1[(d + 2) * 128 + l], w3 = W1[(d + 3) * 128 + l];
#pragma unroll
      for (int i = 0; i < 4; ++i) {
        float4 a4 = *(const float4*)&ar[r0 + 4 * i][d];
        acc[i] += a4.x * w0 + a4.y * w1 + a4.z * w2 + a4.w * w3;
      }
    }
#pragma unroll
    for (int i = 0; i < 4; ++i) keys[(row0 + r0 + 4 * i) * 128 + l] = acc[i];
    return;
  }

  // ---- scan ----
  const _Float16* xz16 = (const _Float16*)(ws + XZ_OFF);
  _Float16* x16 = (_Float16*)((float*)ws + X_OFF);
  const int b_base = blockIdx.x * 4;
  const int w = tid >> 6, lane = tid & 63;
  const int q = lane >> 4, p = lane & 15;
  const int b = p & 3, isel = p >> 2;
  const int u = 16 * w + 4 * isel + q;  // lane's unit
  const int bg = b_base + b;

  // A-frags: lane supplies A[m=p][k=q*8+j]; row m -> gatecol (m&3)*128 + 16w + 4i + (m>>2)
  f16x8 afr[4][4];
#pragma unroll
  for (int i = 0; i < 4; ++i) {
    const int col = (p & 3) * 128 + 16 * w + 4 * i + (p >> 2);
#pragma unroll
    for (int kt = 0; kt < 4; ++kt)
#pragma unroll
      for (int j = 0; j < 8; ++j)
        afr[i][kt][j] = (_Float16)Wrf[(kt * 32 + q * 8 + j) * 512 + col];
  }

  {
    _Float16* hp = &hb[0][0];
    for (int i = tid; i < 2 * 552; i += 512) hp[i] = (_Float16)0.f;
  }
  const fx4 zeroC = {0.f, 0.f, 0.f, 0.f};  // persistent C operand, never written
  float cst = 0.f, hval = 0.f;
  // xz prefetch, 3 deep: 8B/lane/step, stride 4096 f16 per t
  const _Float16* xp = xz16 + (bg * 128 + u) * 4;
  uint2 pf0 = *(const uint2*)(xp);
  uint2 pf1 = *(const uint2*)(xp + 4096);
  uint2 pf2 = *(const uint2*)(xp + 8192);
  __syncthreads();

  const int brow = (p & 3) * 136;  // B broadcast: lanes p>=4 mirror p&3
  for (int t = 0; t < 256; ++t) {
    const _Float16* hrow = &hb[t & 1][brow];
    f16x8 bfr[4];
#pragma unroll
    for (int kt = 0; kt < 4; ++kt)
      bfr[kt] = *(const f16x8*)&hrow[kt * 32 + q * 8];
    fx4 acc[4];
#pragma unroll
    for (int i = 0; i < 4; ++i)
      acc[i] = __builtin_amdgcn_mfma_f32_16x16x32_f16(afr[i][0], bfr[0], zeroC, 0, 0, 0);
#pragma unroll
    for (int kt = 1; kt < 4; ++kt)
#pragma unroll
      for (int i = 0; i < 4; ++i)
        acc[i] = __builtin_amdgcn_mfma_f32_16x16x32_f16(afr[i][kt], bfr[kt], acc[i], 0, 0, 0);

    // select MFMA i = isel (2-bit cndmask tree, no dpp)
    float z[4];
#pragma unroll
    for (int r = 0; r < 4; ++r) {
      float s01 = (isel & 1) ? acc[1][r] : acc[0][r];
      float s23 = (isel & 1) ? acc[3][r] : acc[2][r];
      z[r] = (isel & 2) ? s23 : s01;
    }

    uint2 cur = pf0;
    pf0 = pf1; pf1 = pf2;
    const int t3 = (t + 3 < 256) ? t + 3 : 255;
    pf2 = *(const uint2*)(xp + t3 * 4096);

    const _Float16* cf = (const _Float16*)&cur;
    const float zi = z[0] + (float)cf[0];
    const float zf = z[1] + (float)cf[1];
    const float zg = z[2] + (float)cf[2];
    const float zo = z[3] + (float)cf[3];
    cst = fast_sig(zf) * cst + fast_sig(zi) * fast_tanh(zg);
    hval = fast_sig(zo) * fast_tanh(cst);
    hb[(t + 1) & 1][b * 136 + u] = (_Float16)hval;
    x16[(bg * 256 + t) * 128 + u] = (_Float16)hval;
    LDS_BARRIER();  // LDS visibility only; no vmcnt drain
  }
  out[OUT_H + bg * 128 + u] = hval;
  out[OUT_C + bg * 128 + u] = cst;
}

// ---------------- Kernel 3: qproj + scores + softmax + weighted + concat ----------------
// 512 blocks (4 q-rows each) -> 2 blocks/CU for latency hiding.
__global__ __launch_bounds__(256)
void attn_out_k(const float* __restrict__ att, const float* __restrict__ W2c,
                const float* __restrict__ b2c, const float* __restrict__ W3c,
                const float* __restrict__ b3c, const float* __restrict__ ws,
                float* __restrict__ out) {
  const float* keys = ws + KEYS_OFF;
  const _Float16* x16 = (const _Float16*)(ws + X_OFF);
  __shared__ float qp[4][128];
  __shared__ float xr[4][128];
  __shared__ float sc[4][512];
  __shared__ float kt[64][129];
  __shared__ float w3s[128];
  const int tid = threadIdx.x;
  const int b = blockIdx.x >> 6, q0 = (blockIdx.x & 63) * 4;
  const int l = tid & 127, r0 = tid >> 7;  // r0 in 0..1
  if (tid < 128) w3s[tid] = W3c[tid];
  for (int i = tid; i < 4 * 128; i += 256)
    xr[i >> 7][i & 127] = (float)x16[(b * 256 + q0) * 128 + i];
  __syncthreads();
  {
    float qa[2];
    const float bl = b2c[l];
    qa[0] = bl; qa[1] = bl;
    for (int d = 0; d < 128; d += 4) {
      float w0 = W2c[(d + 0) * 128 + l], w1 = W2c[(d + 1) * 128 + l];
      float w2v = W2c[(d + 2) * 128 + l], w3v = W2c[(d + 3) * 128 + l];
#pragma unroll
      for (int i = 0; i < 2; ++i) {
        float4 a4 = *(const float4*)&xr[r0 + 2 * i][d];
        qa[i] += a4.x * w0 + a4.y * w1 + a4.z * w2v + a4.w * w3v;
      }
    }
#pragma unroll
    for (int i = 0; i < 2; ++i) {
      int rr = r0 + 2 * i;
      qp[rr][l] = qa[i];
      out[(b * 256 + q0 + rr) * 256 + l] = xr[rr][l];
    }
  }
  const float b3v = b3c[0];
  for (int kt0 = 0; kt0 < 512; kt0 += 64) {
    __syncthreads();
    for (int i = tid; i < 64 * 128; i += 256)
      kt[i >> 7][i & 127] = keys[(b * 512 + kt0 + (i >> 7)) * 128 + (i & 127)];
    __syncthreads();
    {
      const int rr = tid >> 6, k = tid & 63;  // 4r x 64k = 256 pairs = 256 threads
      float acc = 0.f;
      for (int ll = 0; ll < 128; ll += 4) {
        float4 q4 = *(const float4*)&qp[rr][ll];
        float4 w4 = *(const float4*)&w3s[ll];
        acc += fast_tanh(kt[k][ll + 0] + q4.x) * w4.x
             + fast_tanh(kt[k][ll + 1] + q4.y) * w4.y
             + fast_tanh(kt[k][ll + 2] + q4.z) * w4.z
             + fast_tanh(kt[k][ll + 3] + q4.w) * w4.w;
      }
      sc[rr][kt0 + k] = acc + b3v;
    }
  }
  __syncthreads();
  {
    const int wave = tid >> 6, lane = tid & 63;  // wave w owns row w
    float v[8];
#pragma unroll
    for (int i = 0; i < 8; ++i) v[i] = sc[wave][lane + i * 64];
    float m = v[0];
#pragma unroll
    for (int i = 1; i < 8; ++i) m = fmaxf(m, v[i]);
#pragma unroll
    for (int off = 32; off > 0; off >>= 1) m = fmaxf(m, __shfl_xor(m, off));
    float e[8], s = 0.f;
#pragma unroll
    for (int i = 0; i < 8; ++i) { e[i] = __expf(v[i] - m); s += e[i]; }
#pragma unroll
    for (int off = 32; off > 0; off >>= 1) s += __shfl_xor(s, off);
    const float inv = fast_rcp(s);
#pragma unroll
    for (int i = 0; i < 8; ++i) sc[wave][lane + i * 64] = e[i] * inv;
  }
  __syncthreads();
  {
    const float* attb = att + b * 512 * 128;
    float wa[2] = {0.f, 0.f};
    for (int k = 0; k < 512; k += 4) {
      float a0 = attb[(k + 0) * 128 + l];
      float a1 = attb[(k + 1) * 128 + l];
      float a2 = attb[(k + 2) * 128 + l];
      float a3 = attb[(k + 3) * 128 + l];
#pragma unroll
      for (int i = 0; i < 2; ++i) {
        float4 p4 = *(const float4*)&sc[r0 + 2 * i][k];
        wa[i] += p4.x * a0 + p4.y * a1 + p4.z * a2 + p4.w * a3;
      }
    }
#pragma unroll
    for (int i = 0; i < 2; ++i)
      out[(b * 256 + q0 + r0 + 2 * i) * 256 + 128 + l] = wa[i];
  }
}

extern "C" void kernel_launch(void* const* d_in, const int* in_sizes, int n_in,
                              void* d_out, int out_size, void* d_ws, size_t ws_size,
                              hipStream_t stream) {
  const float* inputs   = (const float*)d_in[0];
  const float* attended = (const float*)d_in[1];
  const float* Wk       = (const float*)d_in[2];
  const float* Wr       = (const float*)d_in[3];
  const float* bias     = (const float*)d_in[4];
  const float* W1       = (const float*)d_in[5];
  const float* b1       = (const float*)d_in[6];
  const float* W2       = (const float*)d_in[7];
  const float* b2       = (const float*)d_in[8];
  const float* W3       = (const float*)d_in[9];
  const float* b3       = (const float*)d_in[10];
  float* out = (float*)d_out;
  float* ws = (float*)d_ws;

  hipLaunchKernelGGL(xz_prologue, dim3(256), dim3(256), 0, stream, inputs, Wk, bias, ws);
  hipLaunchKernelGGL(lstm_scan, dim3(258), dim3(512), 0, stream,
                     Wr, attended, W1, b1, ws, out);
  hipLaunchKernelGGL(attn_out_k, dim3(512), dim3(256), 0, stream,
                     attended, W2, b2, W3, b3, ws, out);
}